// Round 7
// baseline (477.822 us; speedup 1.0000x reference)
//
#include <hip/hip_runtime.h>
#include <math.h>

#define BB 4
#define SS 2048
#define DD 1024
#define HH 16
#define DHH 64
#define DFF 4096
static constexpr float LN_EPS = 1e-5f;

typedef __bf16 bf16x8 __attribute__((ext_vector_type(8)));
typedef float f32x4 __attribute__((ext_vector_type(4)));
typedef unsigned short u16x8 __attribute__((ext_vector_type(8)));
typedef unsigned int u32x4 __attribute__((ext_vector_type(4)));

// bf16 convert via HW RNE cvt (bit-identical to manual round-to-nearest-even).
__device__ __forceinline__ unsigned short f2bf(float f) {
    return __builtin_bit_cast(unsigned short, (__bf16)f);
}

// Fast 2^x via the gfx hardware exp2 (v_exp_f32).
__device__ __forceinline__ float fexp2(float x) {
    return __builtin_amdgcn_exp2f(x);
}

// Async global->LDS DMA, 16 B/lane; LDS dest = wave-uniform base + lane*16.
__device__ __forceinline__ void gl_lds16(const unsigned short* g,
                                         unsigned short* l) {
    __builtin_amdgcn_global_load_lds(
        (const __attribute__((address_space(1))) unsigned int*)g,
        (__attribute__((address_space(3))) unsigned int*)l, 16, 0, 0);
}

// Raw workgroup barrier with compiler memory fence (no vmcnt drain).
#define GBAR()                               \
    do {                                     \
        asm volatile("" ::: "memory");       \
        __builtin_amdgcn_s_barrier();        \
        asm volatile("" ::: "memory");       \
    } while (0)
#define VMCNT(n) asm volatile("s_waitcnt vmcnt(" #n ")" ::: "memory")

// ---------------------------------------------------------------------------
// fp32 [R][C] -> bf16 transposed [C][R]. 64x64 LDS tiles.
// ---------------------------------------------------------------------------
__global__ __launch_bounds__(256) void transpose_bf16_kernel(
    const float* __restrict__ in, unsigned short* __restrict__ outT,
    int R, int C) {
    __shared__ float t[64][65];
    const int r0 = blockIdx.y * 64, c0 = blockIdx.x * 64;
    const int cl = threadIdx.x & 63, rl = threadIdx.x >> 6;
#pragma unroll
    for (int rr = 0; rr < 16; ++rr)
        t[rl + rr * 4][cl] = in[(size_t)(r0 + rl + rr * 4) * C + c0 + cl];
    __syncthreads();
#pragma unroll
    for (int rr = 0; rr < 16; ++rr)
        outT[(size_t)(c0 + rl + rr * 4) * R + r0 + cl] = f2bf(t[cl][rl + rr * 4]);
}

// ---------------------------------------------------------------------------
// Wqkv [H][D][192] fp32 -> Wq2T bf16 [3072][1024] (row n=h*192+e, col k=d).
// ---------------------------------------------------------------------------
__global__ __launch_bounds__(256) void repack_wqkv_bf16_kernel(
    const float* __restrict__ Wqkv, unsigned short* __restrict__ Wq2T) {
    __shared__ float t[64][65];
    const int h = blockIdx.z;
    const int d0 = blockIdx.y * 64, e0 = blockIdx.x * 64;
    const int cl = threadIdx.x & 63, rl = threadIdx.x >> 6;
#pragma unroll
    for (int rr = 0; rr < 16; ++rr)
        t[rl + rr * 4][cl] =
            Wqkv[((size_t)h * DD + d0 + rl + rr * 4) * 192 + e0 + cl];
    __syncthreads();
#pragma unroll
    for (int rr = 0; rr < 16; ++rr)
        Wq2T[((size_t)h * 192 + e0 + rl + rr * 4) * DD + d0 + cl] =
            f2bf(t[cl][rl + rr * 4]);
}

__global__ __launch_bounds__(256) void f2bf_kernel(
    const float* __restrict__ in, unsigned short* __restrict__ out, int n) {
    int i = blockIdx.x * 256 + threadIdx.x;
    if (i < n) out[i] = f2bf(in[i]);
}

// ---------------------------------------------------------------------------
// Shared staging / fragment helpers (k-chunk XOR swizzle: chunk c of local
// row r holds global chunk c^(r&7); reads apply the same XOR).
// ---------------------------------------------------------------------------
// 128 local rows (2 gl_lds/thread at 512 thr). RS=6: 64-row stripes; RS=5: 32.
template <int RS>
__device__ __forceinline__ void stage_half(const unsigned short* __restrict__ G,
                                           int ldK, int growbase, int kbase,
                                           unsigned short* lbase, int tid) {
#pragma unroll
    for (int s = 0; s < 2; ++s) {
        const int c16 = s * 512 + tid;           // 16B chunk id in half-tile
        const int r = c16 >> 3, c = c16 & 7;     // local row, chunk-in-row
        const int grow =
            growbase + ((r >> RS) << (RS + 1)) + (r & ((1 << RS) - 1));
        const int gcol = kbase + ((c ^ (r & 7)) << 3);
        gl_lds16(&G[(size_t)grow * ldK + gcol], &lbase[c16 << 3]);
    }
}

// 64 local rows, 32-row stripes (2 gl_lds/thread at 256 thr) — gemm128 halves.
__device__ __forceinline__ void stage_h64(const unsigned short* __restrict__ G,
                                          int ldK, int growbase, int kbase,
                                          unsigned short* lbase, int tid) {
#pragma unroll
    for (int s = 0; s < 2; ++s) {
        const int c16 = s * 256 + tid;           // 512 chunks = 64 rows x 8
        const int r = c16 >> 3, c = c16 & 7;
        const int grow = growbase + ((r >> 5) << 6) + (r & 31);
        const int gcol = kbase + ((c ^ (r & 7)) << 3);
        gl_lds16(&G[(size_t)grow * ldK + gcol], &lbase[c16 << 3]);
    }
}

// 64x64 bf16 tile, arbitrary src row stride, natural row order
// (2 gl_lds/thread at 256 threads) — attention V^T tiles.
__device__ __forceinline__ void stage_kv(const unsigned short* __restrict__ src,
                                         size_t rstride, unsigned short* dst,
                                         int tid) {
#pragma unroll
    for (int s = 0; s < 2; ++s) {
        const int c16 = s * 256 + tid;
        const int r = c16 >> 3, c = c16 & 7;
        gl_lds16(&src[(size_t)r * rstride + ((c ^ (r & 7)) << 3)],
                 &dst[c16 << 3]);
    }
}

// K tile with pi row permutation (2 gl_lds/thread at 256 threads):
// LDS row rho holds global K row pi(rho) = 32*(j&1) + 8g + 4*(j>>1) + r2
// (rho = 16j + 4g + r2). This makes each lane's QK^T C-fragment hold exactly
// the kv values its own PV B-fragment needs -> zero cross-lane P exchange.
__device__ __forceinline__ void stage_k_pi(const unsigned short* __restrict__ src,
                                           unsigned short* dst, int tid) {
#pragma unroll
    for (int s = 0; s < 2; ++s) {
        const int c16 = s * 256 + tid;
        const int r = c16 >> 3, c = c16 & 7;
        const int gr = ((r >> 4) & 1) * 32 + (((r >> 2) & 3) << 3) +
                       ((r >> 5) & 1) * 4 + (r & 3);
        gl_lds16(&src[(size_t)gr * 64 + ((c ^ (r & 7)) << 3)],
                 &dst[c16 << 3]);
    }
}

// ---------------------------------------------------------------------------
// 256x256-tile, BK=64, 8-wave, 8-phase software-pipelined bf16 MFMA GEMM.
// (used for MLP-up, MODE 2). Per wave (wm=wave>>2, wn=wave&3): 128x64 output.
// vmcnt(6) at ph4/ph8 only. MODE 2: bf16 out = gelu_tanh(C+bias) LDS repack.
// ---------------------------------------------------------------------------
__device__ __forceinline__ void read_afrag(const unsigned short* s, int base,
                                           int wm, int l15, int g,
                                           bf16x8 af[4][2]) {
#pragma unroll
    for (int ii = 0; ii < 4; ++ii) {
        const int lr = wm * 64 + ii * 16 + l15;
#pragma unroll
        for (int ks = 0; ks < 2; ++ks) {
            const int p = ((ks << 2) + g) ^ (lr & 7);
            af[ii][ks] = __builtin_bit_cast(
                bf16x8, *(const u16x8*)&s[base + lr * 64 + p * 8]);
        }
    }
}

__device__ __forceinline__ void read_bfrag(const unsigned short* s, int base,
                                           int wn, int l15, int g,
                                           bf16x8 bf2[2][2]) {
#pragma unroll
    for (int jj = 0; jj < 2; ++jj) {
        const int lr = wn * 32 + jj * 16 + l15;
#pragma unroll
        for (int ks = 0; ks < 2; ++ks) {
            const int p = ((ks << 2) + g) ^ (lr & 7);
            bf2[jj][ks] = __builtin_bit_cast(
                bf16x8, *(const u16x8*)&s[base + lr * 64 + p * 8]);
        }
    }
}

template <int MH, int NH>
__device__ __forceinline__ void mfma_quad(f32x4 acc[8][4],
                                          const bf16x8 af[4][2],
                                          const bf16x8 bf2[2][2]) {
    __builtin_amdgcn_s_setprio(1);
#pragma unroll
    for (int ks = 0; ks < 2; ++ks)
#pragma unroll
        for (int ii = 0; ii < 4; ++ii)
#pragma unroll
            for (int jj = 0; jj < 2; ++jj)
                acc[MH * 4 + ii][NH * 2 + jj] =
                    __builtin_amdgcn_mfma_f32_16x16x32_bf16(
                        af[ii][ks], bf2[jj][ks],
                        acc[MH * 4 + ii][NH * 2 + jj], 0, 0, 0);
    __builtin_amdgcn_s_setprio(0);
}

template <int MODE>
__global__ __launch_bounds__(512) void mfma_gemm256_kernel(
    const unsigned short* __restrict__ A, const unsigned short* __restrict__ BT,
    float* __restrict__ Cf, unsigned short* __restrict__ Cb,
    const float* __restrict__ bias, const float* __restrict__ resid,
    int M, int N, int K) {
    __shared__ __align__(16) unsigned short smem[65536];  // 128 KiB
    const int tid = threadIdx.x;
    const int lane = tid & 63, wave = tid >> 6;
    const int wm = wave >> 2, wn = wave & 3;
    const int l15 = lane & 15, g = lane >> 4;

    const int gx = gridDim.x, nwg = gx * gridDim.y;
    const int lid = blockIdx.y * gx + blockIdx.x;
    const int swz = ((nwg & 7) == 0) ? ((lid & 7) * (nwg >> 3) + (lid >> 3))
                                     : lid;
    const int row0 = (swz / gx) * 256;
    const int col0 = (swz % gx) * 256;

    const int kt = K >> 6;

    f32x4 acc[8][4] = {};

    stage_half<6>(A, K, row0, 0, smem + 0, tid);           // T0 A h0
    stage_half<6>(A, K, row0 + 64, 0, smem + 8192, tid);   // T0 A h1
    stage_half<5>(BT, K, col0, 0, smem + 32768, tid);      // T0 B h0
    stage_half<5>(BT, K, col0 + 32, 0, smem + 40960, tid); // T0 B h1
    VMCNT(4);
    stage_half<6>(A, K, row0, 64, smem + 16384, tid);      // T1 A h0
    stage_half<6>(A, K, row0 + 64, 64, smem + 24576, tid); // T1 A h1
    stage_half<5>(BT, K, col0, 64, smem + 49152, tid);     // T1 B h0
    VMCNT(6);
    GBAR();

    bf16x8 af[4][2], bf0[2][2], bf1[2][2];
    for (int it = 0; it < (kt >> 1); ++it) {
        const int t1k = (2 * it + 1) << 6;
        int t2 = 2 * it + 2; if (t2 > kt - 1) t2 = kt - 1;
        int t3 = 2 * it + 3; if (t3 > kt - 1) t3 = kt - 1;
        const int t2k = t2 << 6, t3k = t3 << 6;

        read_afrag(smem, 0, wm, l15, g, af);
        read_bfrag(smem, 32768, wn, l15, g, bf0);
        stage_half<5>(BT, K, col0 + 32, t1k, smem + 57344, tid);
        GBAR();
        mfma_quad<0, 0>(acc, af, bf0);
        GBAR();

        read_bfrag(smem, 40960, wn, l15, g, bf1);
        stage_half<6>(A, K, row0, t2k, smem + 0, tid);
        GBAR();
        mfma_quad<0, 1>(acc, af, bf1);
        GBAR();

        read_afrag(smem, 8192, wm, l15, g, af);
        stage_half<5>(BT, K, col0, t2k, smem + 32768, tid);
        GBAR();
        mfma_quad<1, 1>(acc, af, bf1);
        GBAR();

        stage_half<6>(A, K, row0 + 64, t2k, smem + 8192, tid);
        GBAR();
        mfma_quad<1, 0>(acc, af, bf0);
        VMCNT(6);
        GBAR();

        read_afrag(smem, 16384, wm, l15, g, af);
        read_bfrag(smem, 49152, wn, l15, g, bf0);
        stage_half<5>(BT, K, col0 + 32, t2k, smem + 40960, tid);
        GBAR();
        mfma_quad<0, 0>(acc, af, bf0);
        GBAR();

        read_bfrag(smem, 57344, wn, l15, g, bf1);
        stage_half<6>(A, K, row0, t3k, smem + 16384, tid);
        GBAR();
        mfma_quad<0, 1>(acc, af, bf1);
        GBAR();

        read_afrag(smem, 24576, wm, l15, g, af);
        stage_half<5>(BT, K, col0, t3k, smem + 49152, tid);
        GBAR();
        mfma_quad<1, 1>(acc, af, bf1);
        GBAR();

        stage_half<6>(A, K, row0 + 64, t3k, smem + 24576, tid);
        GBAR();
        mfma_quad<1, 0>(acc, af, bf0);
        VMCNT(6);
        GBAR();
    }
    VMCNT(0);
    GBAR();

    if (MODE == 2) {
        constexpr int SLAB = 264;  // 32 x 256 bf16 slab, padded stride
#pragma unroll
        for (int i2 = 0; i2 < 8; ++i2) {
            __syncthreads();
#pragma unroll
            for (int j2 = 0; j2 < 4; ++j2) {
                const int col = wn * 64 + j2 * 16 + l15;
                const float bv = bias[col0 + col];
#pragma unroll
                for (int r = 0; r < 4; ++r) {
                    float v = acc[i2][j2][r] + bv;
                    // gelu_tanh: v * t/(t+1), t = 2^(v*(2.302118+0.102942 v^2))
                    float t = fexp2(v * (2.30211849f + 0.10294198f * v * v));
                    float gel = v * t * __builtin_amdgcn_rcpf(t + 1.f);
                    smem[(wm * 16 + g * 4 + r) * SLAB + col] = f2bf(gel);
                }
            }
            __syncthreads();
            const int sr = tid >> 4;           // 0..31 slab row
            const int cc = (tid & 15) * 16;    // col base
            const int grow = row0 + ((sr >> 4) << 7) + i2 * 16 + (sr & 15);
            *(u16x8*)&Cb[(size_t)grow * N + col0 + cc] =
                *(const u16x8*)&smem[sr * SLAB + cc];
            *(u16x8*)&Cb[(size_t)grow * N + col0 + cc + 8] =
                *(const u16x8*)&smem[sr * SLAB + cc + 8];
        }
        return;
    }

#pragma unroll
    for (int i2 = 0; i2 < 8; ++i2) {
#pragma unroll
        for (int j2 = 0; j2 < 4; ++j2) {
            const int col = col0 + wn * 64 + j2 * 16 + l15;
            const int rowb = row0 + wm * 128 + i2 * 16 + g * 4;
            const float bv = bias[col];
#pragma unroll
            for (int r = 0; r < 4; ++r) {
                const int row = rowb + r;
                float v = acc[i2][j2][r] + bv + resid[(size_t)row * N + col];
                Cf[(size_t)row * N + col] = v;
            }
        }
    }
}

// ---------------------------------------------------------------------------
// 128x128-tile, BK=64, 4-wave (2M x 2N), 8-phase GEMM — 64 KiB LDS ->
// 2 blocks/CU co-resident: one block's MFMA fills the other's barrier/stage
// stalls (the n128 predecessor ran 1 block/CU and was barrier-bound).
// Exact clone of the 256^2 schedule with halved regions (8 KiB halves):
//   A half h local row r (0..63) <-> global tile row (r>>5)*64 + h*32 + (r&31)
//   B identical with col0. vmcnt(4)/(6) counting carries over unchanged.
// Per wave (wm=wave>>1, wn=wave&1): output 64x64, acc[4][4].
// MODE 3: fp32 C+bias+resid. MODE 4: QKV scatter.
// ---------------------------------------------------------------------------
__device__ __forceinline__ void read_af128(const unsigned short* s, int base,
                                           int wm, int l15, int g,
                                           bf16x8 af[2][2]) {
#pragma unroll
    for (int ii = 0; ii < 2; ++ii) {
        const int lr = wm * 32 + ii * 16 + l15;
#pragma unroll
        for (int ks = 0; ks < 2; ++ks) {
            const int p = ((ks << 2) + g) ^ (lr & 7);
            af[ii][ks] = __builtin_bit_cast(
                bf16x8, *(const u16x8*)&s[base + lr * 64 + p * 8]);
        }
    }
}

__device__ __forceinline__ void read_bf128(const unsigned short* s, int base,
                                           int wn, int l15, int g,
                                           bf16x8 bf2[2][2]) {
#pragma unroll
    for (int jj = 0; jj < 2; ++jj) {
        const int lr = wn * 32 + jj * 16 + l15;
#pragma unroll
        for (int ks = 0; ks < 2; ++ks) {
            const int p = ((ks << 2) + g) ^ (lr & 7);
            bf2[jj][ks] = __builtin_bit_cast(
                bf16x8, *(const u16x8*)&s[base + lr * 64 + p * 8]);
        }
    }
}

template <int MH, int NH>
__device__ __forceinline__ void mfma_quad128(f32x4 acc[4][4],
                                             const bf16x8 af[2][2],
                                             const bf16x8 bf2[2][2]) {
    __builtin_amdgcn_s_setprio(1);
#pragma unroll
    for (int ks = 0; ks < 2; ++ks)
#pragma unroll
        for (int ii = 0; ii < 2; ++ii)
#pragma unroll
            for (int jj = 0; jj < 2; ++jj)
                acc[MH * 2 + ii][NH * 2 + jj] =
                    __builtin_amdgcn_mfma_f32_16x16x32_bf16(
                        af[ii][ks], bf2[jj][ks],
                        acc[MH * 2 + ii][NH * 2 + jj], 0, 0, 0);
    __builtin_amdgcn_s_setprio(0);
}

template <int MODE>
__global__ __launch_bounds__(256, 2) void gemm128_kernel(
    const unsigned short* __restrict__ A, const unsigned short* __restrict__ BT,
    float* __restrict__ Cf, const float* __restrict__ bias,
    const float* __restrict__ resid, unsigned short* __restrict__ Qb,
    unsigned short* __restrict__ Kb, unsigned short* __restrict__ VTb,
    int M, int N, int K) {
    __shared__ __align__(16) unsigned short smem[32768];  // 64 KiB
    const int tid = threadIdx.x;
    const int lane = tid & 63, wave = tid >> 6;           // wave 0..3
    const int wm = wave >> 1, wn = wave & 1;
    const int l15 = lane & 15, g = lane >> 4;

    const int gx = gridDim.x, nwg = gx * gridDim.y;
    const int lid = blockIdx.y * gx + blockIdx.x;
    const int swz = ((nwg & 7) == 0) ? ((lid & 7) * (nwg >> 3) + (lid >> 3))
                                     : lid;
    const int row0 = (swz / gx) * 128;
    const int col0 = (swz % gx) * 128;

    const int kt = K >> 6;

    // LDS regions (elems): A even{h0,h1}=0,4096; A odd{h0,h1}=8192,12288;
    //                      B even{h0,h1}=16384,20480; B odd{h0,h1}=24576,28672
    f32x4 acc[4][4] = {};

    stage_h64(A, K, row0, 0, smem + 0, tid);              // T0 A h0
    stage_h64(A, K, row0 + 32, 0, smem + 4096, tid);      // T0 A h1
    stage_h64(BT, K, col0, 0, smem + 16384, tid);         // T0 B h0
    stage_h64(BT, K, col0 + 32, 0, smem + 20480, tid);    // T0 B h1
    VMCNT(4);
    stage_h64(A, K, row0, 64, smem + 8192, tid);          // T1 A h0
    stage_h64(A, K, row0 + 32, 64, smem + 12288, tid);    // T1 A h1
    stage_h64(BT, K, col0, 64, smem + 24576, tid);        // T1 B h0
    VMCNT(6);
    GBAR();

    bf16x8 af[2][2], bf0[2][2], bf1[2][2];
    for (int it = 0; it < (kt >> 1); ++it) {
        const int t1k = (2 * it + 1) << 6;
        int t2 = 2 * it + 2; if (t2 > kt - 1) t2 = kt - 1;   // clamped
        int t3 = 2 * it + 3; if (t3 > kt - 1) t3 = kt - 1;   // (junk re-stage,
        const int t2k = t2 << 6, t3k = t3 << 6;              //  dest dead)

        read_af128(smem, 0, wm, l15, g, af);
        read_bf128(smem, 16384, wn, l15, g, bf0);
        stage_h64(BT, K, col0 + 32, t1k, smem + 28672, tid);
        GBAR();
        mfma_quad128<0, 0>(acc, af, bf0);
        GBAR();

        read_bf128(smem, 20480, wn, l15, g, bf1);
        stage_h64(A, K, row0, t2k, smem + 0, tid);
        GBAR();
        mfma_quad128<0, 1>(acc, af, bf1);
        GBAR();

        read_af128(smem, 4096, wm, l15, g, af);
        stage_h64(BT, K, col0, t2k, smem + 16384, tid);
        GBAR();
        mfma_quad128<1, 1>(acc, af, bf1);
        GBAR();

        stage_h64(A, K, row0 + 32, t2k, smem + 4096, tid);
        GBAR();
        mfma_quad128<1, 0>(acc, af, bf0);
        VMCNT(6);
        GBAR();

        read_af128(smem, 8192, wm, l15, g, af);
        read_bf128(smem, 24576, wn, l15, g, bf0);
        stage_h64(BT, K, col0 + 32, t2k, smem + 20480, tid);
        GBAR();
        mfma_quad128<0, 0>(acc, af, bf0);
        GBAR();

        read_bf128(smem, 28672, wn, l15, g, bf1);
        stage_h64(A, K, row0, t3k, smem + 8192, tid);
        GBAR();
        mfma_quad128<0, 1>(acc, af, bf1);
        GBAR();

        read_af128(smem, 12288, wm, l15, g, af);
        stage_h64(BT, K, col0, t3k, smem + 24576, tid);
        GBAR();
        mfma_quad128<1, 1>(acc, af, bf1);
        GBAR();

        stage_h64(A, K, row0 + 32, t3k, smem + 12288, tid);
        GBAR();
        mfma_quad128<1, 0>(acc, af, bf0);
        VMCNT(6);
        GBAR();
    }
    VMCNT(0);  // drain junk prefetches before exit
    GBAR();

#pragma unroll
    for (int i2 = 0; i2 < 4; ++i2) {
#pragma unroll
        for (int j2 = 0; j2 < 4; ++j2) {
            const int col = col0 + wn * 64 + j2 * 16 + l15;
            const int rowb = row0 + wm * 64 + i2 * 16 + g * 4;
            if (MODE == 4) {
                const int h = col / 192, e = col % 192;
                const int bb = rowb >> 11, s = rowb & 2047;
                if (e < 64) {
                    unsigned short* q =
                        Qb + (((size_t)bb * HH + h) * SS + s) * 64 + e;
#pragma unroll
                    for (int r = 0; r < 4; ++r)
                        q[r * 64] = f2bf(acc[i2][j2][r] * 0.18033688f);
                } else if (e < 128) {
                    unsigned short* kp =
                        Kb + (((size_t)bb * HH + h) * SS + s) * 64 + (e - 64);
#pragma unroll
                    for (int r = 0; r < 4; ++r)
                        kp[r * 64] = f2bf(acc[i2][j2][r]);
                } else {
                    ushort4 pk;
                    pk.x = f2bf(acc[i2][j2][0]);
                    pk.y = f2bf(acc[i2][j2][1]);
                    pk.z = f2bf(acc[i2][j2][2]);
                    pk.w = f2bf(acc[i2][j2][3]);
                    *(ushort4*)(VTb + (((size_t)bb * HH + h) * 64 + (e - 128)) *
                                          SS + s) = pk;
                }
            } else {
                const float bv = bias[col];
#pragma unroll
                for (int r = 0; r < 4; ++r) {
                    const int row = rowb + r;
                    float v = acc[i2][j2][r] + bv + resid[(size_t)row * N + col];
                    Cf[(size_t)row * N + col] = v;
                }
            }
        }
    }
}

// ---------------------------------------------------------------------------
// Flash causal attention, transposed-score formulation, exp2 domain
// (Q pre-scaled by 0.125*log2e in the QKV epilogue).
// S^T = K Q^T; softmax per q-col (2 shuffles); O^T = V^T P^T.
// Block: 4 waves; each block processes TWO 128-q chunks {p, 15-p} of one
// (b,h) SEQUENTIALLY -> identical work per block (34 kv tiles), grid 64x8 =
// 512 blocks = exactly 2/CU, all co-resident. Wave owns 32 q (2x16 strips).
// K rows staged pi-PERMUTED (pi(16j+4g+r) = 32(j&1)+8g+4(j>>1)+r): each
// lane's QK^T C-frag then holds exactly its PV B-frag kv set -> the P
// exchange is LANE-LOCAL (pf = {Aw[ks],Bw[ks],Aw[2+ks],Bw[2+ks]}); zero
// ds_bpermute. Causal mask uses pi'd kv indices. LDS = K/V dbuf (32 KiB).
// vmcnt(4) counted prefetch; 2 barriers/tile.
// Defer-max (bit-exact, THR=0): skip O-rescale when __all(mx <= mst).
// ---------------------------------------------------------------------------
__global__ __launch_bounds__(256, 2) void fattn_kernel(
    const unsigned short* __restrict__ Qb, const unsigned short* __restrict__ Kb,
    const unsigned short* __restrict__ VTb, unsigned short* __restrict__ att) {
    __shared__ __align__(16) unsigned short Kls[2][64 * 64];
    __shared__ __align__(16) unsigned short VTls[2][64 * 64];

    const int bh = blockIdx.x;
    const int p = blockIdx.y;                    // 0..7 -> chunks {p, 15-p}
    const int tid = threadIdx.x;
    const int lane = tid & 63;
    const int wave = tid >> 6;                   // 0..3
    const int l15 = lane & 15;
    const int g = lane >> 4;
    const int b = bh >> 4, h = bh & 15;
    const int xh = l15 & 7;

    const unsigned short* Qh = Qb + (size_t)bh * SS * 64;
    const unsigned short* Kh = Kb + (size_t)bh * SS * 64;
    const unsigned short* Vh = VTb + (size_t)bh * 64 * SS;

#pragma unroll 1
    for (int half = 0; half < 2; ++half) {
        const int cidx = half ? (15 - p) : p;    // chunk index 0..15
        const int q0c = cidx << 7;
        const int qw = q0c + wave * 32;          // wave's first q row
        const int qlim = qw + 31;
        const int nt = (cidx << 1) + 2;          // kv tiles for this chunk

        // Q fragments straight from global (wave-private rows), 2 strips.
        bf16x8 qf[2][2];
#pragma unroll
        for (int i = 0; i < 2; ++i)
#pragma unroll
            for (int ks = 0; ks < 2; ++ks)
                qf[i][ks] = __builtin_bit_cast(
                    bf16x8, *(const u16x8*)&Qh[(size_t)(qw + i * 16 + l15) * 64 +
                                               ks * 32 + g * 8]);

        f32x4 oacc[4][2] = {};                   // O^T: [jo=dh][i=strip]
        float mst[2], lst[2];
#pragma unroll
        for (int i = 0; i < 2; ++i) { mst[i] = -1e30f; lst[i] = 0.f; }

        stage_k_pi(Kh, &Kls[0][0], tid);
        stage_kv(Vh, SS, &VTls[0][0], tid);

        for (int t = 0; t < nt; ++t) {
            const int t0 = t << 6;
            if (t + 1 < nt) {
                stage_k_pi(Kh + ((size_t)(t + 1) << 6) * 64,
                           &Kls[(t + 1) & 1][0], tid);
                stage_kv(Vh + ((t + 1) << 6), SS, &VTls[(t + 1) & 1][0], tid);
                VMCNT(4);   // tile t resident; t+1's 4 in flight
            } else {
                VMCNT(0);   // last tile: drain
            }
            GBAR();

            if (t0 <= qlim) {
                const unsigned short* Kt = &Kls[t & 1][0];
                const unsigned short* Vt = &VTls[t & 1][0];

                // ---- S^T = K Q^T (both strips share kb) ----
                f32x4 sacc[4][2] = {};
                __builtin_amdgcn_s_setprio(1);
#pragma unroll
                for (int ks = 0; ks < 2; ++ks) {
                    const int ko = ((((ks << 2) + g) ^ xh) << 3);
                    bf16x8 kb[4];
#pragma unroll
                    for (int j = 0; j < 4; ++j)
                        kb[j] = __builtin_bit_cast(
                            bf16x8,
                            *(const u16x8*)&Kt[(j * 16 + l15) * 64 + ko]);
#pragma unroll
                    for (int j = 0; j < 4; ++j)
#pragma unroll
                        for (int i = 0; i < 2; ++i)
                            sacc[j][i] =
                                __builtin_amdgcn_mfma_f32_16x16x32_bf16(
                                    kb[j], qf[i][ks], sacc[j][i], 0, 0, 0);
                }
                __builtin_amdgcn_s_setprio(0);

                // ---- causal mask (pi'd kv indices) ----
                if (t0 + 63 > qw) {
#pragma unroll
                    for (int j = 0; j < 4; ++j) {
                        const int kgb = t0 + ((j & 1) << 5) + (g << 3) +
                                        ((j >> 1) << 2);
#pragma unroll
                        for (int i = 0; i < 2; ++i) {
                            const int qgi = qw + i * 16 + l15;
#pragma unroll
                            for (int r = 0; r < 4; ++r)
                                if (kgb + r > qgi) sacc[j][i][r] = -1e30f;
                        }
                    }
                }

                // ---- online softmax (exp2 domain), P lane-local ----
                unsigned int Aw[2][4], Bw[2][4];
#pragma unroll
                for (int i = 0; i < 2; ++i) {
                    float mx = -1e30f;
#pragma unroll
                    for (int j = 0; j < 4; ++j)
                        mx = fmaxf(mx,
                                   fmaxf(fmaxf(sacc[j][i][0], sacc[j][i][1]),
                                         fmaxf(sacc[j][i][2], sacc[j][i][3])));
                    mx = fmaxf(mx, __shfl_xor(mx, 16));
                    mx = fmaxf(mx, __shfl_xor(mx, 32));
                    const bool grow = !__all(mx <= mst[i]);
                    float al = 1.f;
                    if (grow) {
                        const float mn = fmaxf(mst[i], mx);
                        al = fexp2(mst[i] - mn);
                        mst[i] = mn;
                    }
                    const float mm = mst[i];
                    float rsum = 0.f;
#pragma unroll
                    for (int j = 0; j < 4; ++j) {
                        float p0 = fexp2(sacc[j][i][0] - mm);
                        float p1 = fexp2(sacc[j][i][1] - mm);
                        float p2 = fexp2(sacc[j][i][2] - mm);
                        float p3 = fexp2(sacc[j][i][3] - mm);
                        rsum += (p0 + p1) + (p2 + p3);
                        Aw[i][j] = (unsigned int)f2bf(p0) |
                                   ((unsigned int)f2bf(p1) << 16);
                        Bw[i][j] = (unsigned int)f2bf(p2) |
                                   ((unsigned int)f2bf(p3) << 16);
                    }
                    rsum += __shfl_xor(rsum, 16);
                    rsum += __shfl_xor(rsum, 32);
                    if (grow) {
                        lst[i] = lst[i] * al + rsum;
#pragma unroll
                        for (int jo = 0; jo < 4; ++jo)
#pragma unroll
                            for (int r = 0; r < 4; ++r) oacc[jo][i][r] *= al;
                    } else {
                        lst[i] += rsum;
                    }
                }

                // ---- O^T += V^T P^T (pf fully lane-local via pi) ----
#pragma unroll
                for (int ks = 0; ks < 2; ++ks) {
                    const int ko = ((((ks << 2) + g) ^ xh) << 3);
                    bf16x8 vb[4];
#pragma unroll
                    for (int jo = 0; jo < 4; ++jo)
                        vb[jo] = __builtin_bit_cast(
                            bf16x8,
                            *(const u16x8*)&Vt[(jo * 16 + l15) * 64 + ko]);
                    __builtin_amdgcn_s_setprio(1);
#pragma unroll
                    for (int i = 0; i < 2; ++i) {
                        u32x4 pw;
                        pw[0] = Aw[i][ks];
                        pw[1] = Bw[i][ks];
                        pw[2] = Aw[i][2 + ks];
                        pw[3] = Bw[i][2 + ks];
                        const bf16x8 pf = __builtin_bit_cast(bf16x8, pw);
#pragma unroll
                        for (int jo = 0; jo < 4; ++jo)
                            oacc[jo][i] =
                                __builtin_amdgcn_mfma_f32_16x16x32_bf16(
                                    vb[jo], pf, oacc[jo][i], 0, 0, 0);
                    }
                    __builtin_amdgcn_s_setprio(0);
                }
            }
            GBAR();   // reads of buf[t&1] done before next overwrite
        }

        // ---- epilogue: O^T/l -> att[b, q, h*64+dh] ----
#pragma unroll
        for (int i = 0; i < 2; ++i) {
            const float inv = 1.f / lst[i];
            const int qg = qw + i * 16 + l15;
            unsigned short* dst =
                att + ((size_t)b * SS + qg) * DD + h * 64 + g * 4;
#pragma unroll
            for (int jo = 0; jo < 4; ++jo) {
                ushort4 pk;
                pk.x = f2bf(oacc[jo][i][0] * inv);
                pk.y = f2bf(oacc[jo][i][1] * inv);
                pk.z = f2bf(oacc[jo][i][2] * inv);
                pk.w = f2bf(oacc[jo][i][3] * inv);
                *(ushort4*)(dst + jo * 16) = pk;
            }
        }
        GBAR();   // epilogue is LDS-independent; sync before next chunk stage
    }
}

// ---------------------------------------------------------------------------
// LayerNorm over D=1024; optional bf16 copy. In-place safe.
// ---------------------------------------------------------------------------
__global__ __launch_bounds__(256) void ln_kernel(
    const float* __restrict__ X, const float* __restrict__ g,
    const float* __restrict__ bta, float* __restrict__ Y,
    unsigned short* __restrict__ Yb) {
    const int row = blockIdx.x;
    const float4 xv = ((const float4*)(X + (size_t)row * DD))[threadIdx.x];

    __shared__ float red1[4], red2[4];
    float s = xv.x + xv.y + xv.z + xv.w;
#pragma unroll
    for (int off = 32; off > 0; off >>= 1) s += __shfl_down(s, off);
    const int wave = threadIdx.x >> 6;
    if ((threadIdx.x & 63) == 0) red1[wave] = s;
    __syncthreads();
    const float mu = (red1[0] + red1[1] + red1[2] + red1[3]) * (1.f / DD);

    float dx = xv.x - mu, dy = xv.y - mu, dz = xv.z - mu, dw = xv.w - mu;
    float s2 = dx * dx + dy * dy + dz * dz + dw * dw;
#pragma unroll
    for (int off = 32; off > 0; off >>= 1) s2 += __shfl_down(s2, off);
    if ((threadIdx.x & 63) == 0) red2[wave] = s2;
    __syncthreads();
    const float var = (red2[0] + red2[1] + red2[2] + red2[3]) * (1.f / DD);
    const float rstd = rsqrtf(var + LN_EPS);

    const float4 gv = ((const float4*)g)[threadIdx.x];
    const float4 bv = ((const float4*)bta)[threadIdx.x];
    float4 yv;
    yv.x = dx * rstd * gv.x + bv.x;
    yv.y = dy * rstd * gv.y + bv.y;
    yv.z = dz * rstd * gv.z + bv.z;
    yv.w = dw * rstd * gv.w + bv.w;
    ((float4*)(Y + (size_t)row * DD))[threadIdx.x] = yv;
    if (Yb) {
        ushort4 q;
        q.x = f2bf(yv.x); q.y = f2bf(yv.y);
        q.z = f2bf(yv.z); q.w = f2bf(yv.w);
        ((ushort4*)(Yb + (size_t)row * DD))[threadIdx.x] = q;
    }
}

// ---------------------------------------------------------------------------
// Workspace (byte offsets, peak 144 MB):
//   [0,16M)    Qb bf16 (ph2-3) -> out1b bf16 (ph5+)
//   [16M,32M)  Kb; [32M,48M) VTb (ph2-3) -> hbuf bf16 [16M,80M) (ph6-7)
//   [96M,102M) Wq2T; [102M,118M) xb (ph1-2)
//   [96M,112M) att bf16 (ph3-4); [96M,128M) out1 fp32 (ph5-7)
//   [118M,120M) WprojT; [128M,136M) W1T; [136M,144M) W2T
// ---------------------------------------------------------------------------
extern "C" void kernel_launch(void* const* d_in, const int* in_sizes, int n_in,
                              void* d_out, int out_size, void* d_ws,
                              size_t ws_size, hipStream_t stream) {
    const float* x     = (const float*)d_in[0];
    const float* Wqkv  = (const float*)d_in[1];
    const float* Wproj = (const float*)d_in[2];
    const float* bproj = (const float*)d_in[3];
    const float* ln1_g = (const float*)d_in[4];
    const float* ln1_b = (const float*)d_in[5];
    const float* ln2_g = (const float*)d_in[6];
    const float* ln2_b = (const float*)d_in[7];
    const float* W1    = (const float*)d_in[8];
    const float* b1    = (const float*)d_in[9];
    const float* W2    = (const float*)d_in[10];
    const float* b2    = (const float*)d_in[11];
    float* out = (float*)d_out;

    const size_t M = (size_t)BB * SS;     // 8192
    const size_t MB = 1024 * 1024;
    char* w = (char*)d_ws;
    unsigned short* Qb     = (unsigned short*)(w + 0);
    unsigned short* out1b  = (unsigned short*)(w + 0);
    unsigned short* Kb     = (unsigned short*)(w + 16 * MB);
    unsigned short* VTb    = (unsigned short*)(w + 32 * MB);
    unsigned short* hbuf   = (unsigned short*)(w + 16 * MB);
    unsigned short* Wq2T   = (unsigned short*)(w + 96 * MB);
    unsigned short* xb     = (unsigned short*)(w + 102 * MB);
    unsigned short* att    = (unsigned short*)(w + 96 * MB);
    float*          out1   = (float*)(w + 96 * MB);
    unsigned short* WprojT = (unsigned short*)(w + 118 * MB);
    unsigned short* W1T    = (unsigned short*)(w + 128 * MB);
    unsigned short* W2T    = (unsigned short*)(w + 136 * MB);

    // 1. weight/input conversions
    repack_wqkv_bf16_kernel<<<dim3(3, 16, 16), 256, 0, stream>>>(Wqkv, Wq2T);
    transpose_bf16_kernel<<<dim3(16, 16), 256, 0, stream>>>(Wproj, WprojT, 1024, 1024);
    transpose_bf16_kernel<<<dim3(64, 16), 256, 0, stream>>>(W1, W1T, 1024, 4096);
    transpose_bf16_kernel<<<dim3(16, 64), 256, 0, stream>>>(W2, W2T, 4096, 1024);
    f2bf_kernel<<<(int)((M * DD + 255) / 256), 256, 0, stream>>>(x, xb, (int)(M * DD));

    // 2. QKV GEMM -> flash layouts Qb/Kb/VTb (bf16, Q in exp2 domain)
    gemm128_kernel<4><<<dim3(3072 / 128, M / 128), 256, 0, stream>>>(
        xb, Wq2T, nullptr, nullptr, nullptr, Qb, Kb, VTb, (int)M, 3072, 1024);

    // 3. flash causal attention -> att bf16 (4-wave equal-work chunk pairs)
    fattn_kernel<<<dim3(BB * HH, 8), 256, 0, stream>>>(Qb, Kb, VTb, att);

    // 4. proj GEMM + bias + residual(x) -> d_out fp32
    gemm128_kernel<3><<<dim3(1024 / 128, M / 128), 256, 0, stream>>>(
        att, WprojT, out, bproj, x, nullptr, nullptr, nullptr,
        (int)M, 1024, 1024);

    // 5. LN1 -> out1 fp32 + out1b bf16
    ln_kernel<<<(int)M, 256, 0, stream>>>(out, ln1_g, ln1_b, out1, out1b);

    // 6. MLP up + GELU -> hbuf bf16
    mfma_gemm256_kernel<2><<<dim3(4096 / 256, M / 256), 512, 0, stream>>>(
        out1b, W1T, nullptr, hbuf, b1, nullptr, (int)M, 4096, 1024);

    // 7. MLP down + bias + residual(out1) -> d_out fp32
    gemm128_kernel<3><<<dim3(1024 / 128, M / 128), 256, 0, stream>>>(
        hbuf, W2T, out, b2, out1, nullptr, nullptr, nullptr,
        (int)M, 1024, 4096);

    // 8. LN2 in-place on d_out
    ln_kernel<<<(int)M, 256, 0, stream>>>(out, ln2_g, ln2_b, out, nullptr);
}